// Round 5
// baseline (349.241 us; speedup 1.0000x reference)
//
#include <hip/hip_runtime.h>

typedef __attribute__((ext_vector_type(4))) float floatx4;
typedef __attribute__((ext_vector_type(8))) short short8;

__device__ __forceinline__ unsigned short f2bf(float f) {
    union { float f; unsigned int i; } v; v.f = f;
    unsigned int x = v.i;
    unsigned int r = (x + 0x7FFFu + ((x >> 16) & 1u)) >> 16;   // RNE
    return (unsigned short)r;
}

// packed f32x2 -> bf16x2 (RNE), hw convert
__device__ __forceinline__ unsigned int cvtpk_bf16(float lo, float hi) {
    unsigned int r;
    asm("v_cvt_pk_bf16_f32 %0, %1, %2" : "=v"(r) : "v"(lo), "v"(hi));
    return r;
}

// DPP lane-permute helper (VALU-latency cross-lane, no LDS pipe).
template<int CTRL>
__device__ __forceinline__ float dppf(float x) {
    return __int_as_float(__builtin_amdgcn_update_dpp(
        0, __float_as_int(x), CTRL, 0xF, 0xF, false));
}

// ---------------- prep: rearrange phi (1024x24) and W (256x256) into bf16
// MFMA B-fragment order in workspace.
// phiF: [kstep 0..31][ntile 0..1][lane 0..63][j 0..7]  (32768 bf16 = 64KB)
// WF  : [ntile 0..15][kstep 0..7][lane 0..63][j 0..7]  (65536 bf16 = 128KB)
__global__ void mhc_prep(const float* __restrict__ phi, const float* __restrict__ W,
                         unsigned short* __restrict__ phiF, unsigned short* __restrict__ WF) {
    int e = blockIdx.x * 256 + threadIdx.x;
    if (e < 32768) {
        int j = e & 7, lane = (e >> 3) & 63, nt = (e >> 9) & 1, ks = e >> 10;
        int n = nt * 16 + (lane & 15);
        int k = ks * 32 + ((lane >> 4) & 3) * 8 + j;
        float v = (n < 24) ? phi[k * 24 + n] : 0.0f;
        phiF[e] = f2bf(v);
    } else {
        int e2 = e - 32768;
        int j = e2 & 7, lane = (e2 >> 3) & 63, ks = (e2 >> 9) & 7, nt = e2 >> 12;
        int n = nt * 16 + (lane & 15);
        int k = ks * 32 + ((lane >> 4) & 3) * 8 + j;
        WF[e2] = f2bf(W[n * 256 + k]);
    }
}

// ================= kernel 1: front = stage + logits + rms/sigmoid ==========
// 8 tokens/block. LDS = 16.5K(xs) + 1.8K(lgp) = 18.3KB -> 8 blocks/CU (wave
// cap). 3 barriers, NO Sinkhorn. Writes cbuf[tok][0:8]=h, [8:24]=y (pre-exp).
#define TOK 8
#define XS_STRIDE 1032   // bf16; 2064B rows
#define CO_STRIDE 28     // floats

__global__ __launch_bounds__(256, 8) void mhc_front(
    const float* __restrict__ x, const float* __restrict__ bias,
    const float* __restrict__ s_ap, const float* __restrict__ s_apo,
    const unsigned short* __restrict__ phiF,
    float* __restrict__ cbuf)
{
    __shared__ alignas(16) unsigned short xs[TOK * XS_STRIDE];
    __shared__ alignas(16) float lgp[2][TOK * CO_STRIDE];

    const int t = threadIdx.x;
    const int lane = t & 63;
    const int w = t >> 6;
    const int quad = lane >> 4;
    const int col = lane & 15;
    const long base = (long)blockIdx.x * (TOK * 1024);

    // ---- phase 0: global f32 -> bf16 LDS ----
    {
        const float4* xg = (const float4*)(x + base);
        #pragma unroll
        for (int ii = 0; ii < TOK; ++ii) {
            float4 v = xg[ii * 256 + t];
            uint2 pk;
            pk.x = cvtpk_bf16(v.x, v.y);
            pk.y = cvtpk_bf16(v.z, v.w);
            *reinterpret_cast<uint2*>(&xs[ii * XS_STRIDE + t * 4]) = pk;
        }
    }
    __syncthreads();

    // ---- phase 1: logits = V(8x1024) @ phi(1024x24), split-K over 4 waves ----
    {
        floatx4 acc = {0.0f, 0.0f, 0.0f, 0.0f};
        const int ntile = w & 1;
        const int kh = w >> 1;
        const int arow = col & 7;
        for (int ks = kh * 16; ks < kh * 16 + 16; ++ks) {
            short8 a = *reinterpret_cast<const short8*>(&xs[arow * XS_STRIDE + ks * 32 + quad * 8]);
            short8 b = *reinterpret_cast<const short8*>(&phiF[(ks * 2 + ntile) * 512 + lane * 8]);
            acc = __builtin_amdgcn_mfma_f32_16x16x32_bf16(a, b, acc, 0, 0, 0);
        }
        int n = ntile * 16 + col;
        if (n < 24 && quad < 2) {
            #pragma unroll
            for (int r = 0; r < 4; ++r)
                lgp[kh][(quad * 4 + r) * CO_STRIDE + n] = acc[r];
        }
    }
    __syncthreads();

    // ---- phase 2: rms-norm + sigmoids; write h and pre-Sinkhorn y ----
    if (t < 128) {
        int g = t >> 4, p = t & 15;
        const float* l0 = lgp[0] + g * CO_STRIDE;
        const float* l1 = lgp[1] + g * CO_STRIDE;
        float a  = l0[p] + l1[p];
        float b2 = (p < 8) ? (l0[16 + p] + l1[16 + p]) : 0.0f;
        float s = a * a + b2 * b2;
        s += dppf<0x121>(s);   // row_ror:1
        s += dppf<0x122>(s);   // row_ror:2
        s += dppf<0x124>(s);   // row_ror:4
        s += dppf<0x128>(s);   // row_ror:8   -> 16-lane allreduce (24 vals)
        float rinv = 1.0f / sqrtf(s * (1.0f / 24.0f) + 1e-6f);
        long tok = (long)blockIdx.x * TOK + g;
        float* cb = cbuf + tok * 24;
        cb[8 + p] = (l0[8 + p] + l1[8 + p]) * rinv + bias[8 + p];  // y_res (pre-exp)
        if (p < 8) {
            float yh = a * rinv + bias[p];
            float h = (p < 4) ? 1.0f / (1.0f + expf(-s_ap[0] * yh))
                              : 2.0f / (1.0f + expf(-s_apo[0] * yh));
            cb[p] = h;
        }
    }
}

// ================= kernel 2: sink = Sinkhorn, one token per LANE ===========
// Fully in-lane (16 scalar P's, zero cross-lane ops), 64 tokens/wave packed.
// In-place on cbuf[tok][8:24]: reads y, writes P.
__global__ __launch_bounds__(64) void mhc_sink(
    float* __restrict__ cbuf, const float* __restrict__ s_ar)
{
    const long tok = (long)blockIdx.x * 64 + threadIdx.x;
    float* cb = cbuf + tok * 24 + 8;
    const float ar = s_ar[0];
    float4 y0 = *reinterpret_cast<const float4*>(cb);
    float4 y1 = *reinterpret_cast<const float4*>(cb + 4);
    float4 y2 = *reinterpret_cast<const float4*>(cb + 8);
    float4 y3 = *reinterpret_cast<const float4*>(cb + 12);
    float p0 = expf(ar*y0.x), p1 = expf(ar*y0.y), p2 = expf(ar*y0.z), p3 = expf(ar*y0.w);
    float p4 = expf(ar*y1.x), p5 = expf(ar*y1.y), p6 = expf(ar*y1.z), p7 = expf(ar*y1.w);
    float p8 = expf(ar*y2.x), p9 = expf(ar*y2.y), pa = expf(ar*y2.z), pb = expf(ar*y2.w);
    float pc = expf(ar*y3.x), pd = expf(ar*y3.y), pe = expf(ar*y3.z), pf = expf(ar*y3.w);
    #pragma unroll
    for (int it = 0; it < 20; ++it) {
        // row sums (axis -1): 4 independent trees -> full ILP
        float r0 = __builtin_amdgcn_rcpf(((p0+p1)+(p2+p3)) + 1e-6f);
        float r1 = __builtin_amdgcn_rcpf(((p4+p5)+(p6+p7)) + 1e-6f);
        float r2 = __builtin_amdgcn_rcpf(((p8+p9)+(pa+pb)) + 1e-6f);
        float r3 = __builtin_amdgcn_rcpf(((pc+pd)+(pe+pf)) + 1e-6f);
        p0*=r0; p1*=r0; p2*=r0; p3*=r0;
        p4*=r1; p5*=r1; p6*=r1; p7*=r1;
        p8*=r2; p9*=r2; pa*=r2; pb*=r2;
        pc*=r3; pd*=r3; pe*=r3; pf*=r3;
        // col sums (axis -2)
        float c0 = __builtin_amdgcn_rcpf(((p0+p4)+(p8+pc)) + 1e-6f);
        float c1 = __builtin_amdgcn_rcpf(((p1+p5)+(p9+pd)) + 1e-6f);
        float c2 = __builtin_amdgcn_rcpf(((p2+p6)+(pa+pe)) + 1e-6f);
        float c3 = __builtin_amdgcn_rcpf(((p3+p7)+(pb+pf)) + 1e-6f);
        p0*=c0; p4*=c0; p8*=c0; pc*=c0;
        p1*=c1; p5*=c1; p9*=c1; pd*=c1;
        p2*=c2; p6*=c2; pa*=c2; pe*=c2;
        p3*=c3; p7*=c3; pb*=c3; pf*=c3;
    }
    float4 o0 = {p0,p1,p2,p3}, o1 = {p4,p5,p6,p7}, o2 = {p8,p9,pa,pb}, o3 = {pc,pd,pe,pf};
    *reinterpret_cast<float4*>(cb)      = o0;
    *reinterpret_cast<float4*>(cb + 4)  = o1;
    *reinterpret_cast<float4*>(cb + 8)  = o2;
    *reinterpret_cast<float4*>(cb + 12) = o3;
}

// ================= kernel 3: apply = xin + W-GEMM + P-mix ==================
// 8 tokens/block. x read from global (L3-hot after front; L2-hot on re-read).
// LDS = 4.2K(xin) + 0.8K(coef) = 5KB -> 8 blocks/CU. 2 barriers.
#define XIN_STRIDE 264   // bf16; 528B rows

__global__ __launch_bounds__(256, 8) void mhc_apply(
    const float* __restrict__ x, const float* __restrict__ cbuf,
    const unsigned short* __restrict__ WF, float* __restrict__ out)
{
    __shared__ alignas(16) unsigned short xin[TOK * XIN_STRIDE];
    __shared__ alignas(16) float coef[TOK * 24];   // [hpre0..3,hpost0..3,P[16]]

    const int t = threadIdx.x;
    const int lane = t & 63;
    const int w = t >> 6;
    const int quad = lane >> 4;
    const int col = lane & 15;
    const long base = (long)blockIdx.x * (TOK * 1024);

    // ---- load coefficients (192 floats) ----
    if (t < 192) coef[t] = cbuf[(long)blockIdx.x * (TOK * 24) + t];
    __syncthreads();

    // ---- phase 3: x_in[tok][c] = sum_i hpre[i]*x[tok][i][c], f32 x global ----
    // thread: 4 consecutive c (float4), wave w handles tokens 2w, 2w+1
    {
        const int cc = (t & 63) * 4;
        const int tok0 = w * 2;
        #pragma unroll
        for (int s = 0; s < 2; ++s) {
            int tok = tok0 + s;
            float4 h4 = *reinterpret_cast<const float4*>(&coef[tok * 24]);
            const float* xr = x + base + tok * 1024 + cc;
            float4 x0 = *reinterpret_cast<const float4*>(xr);
            float4 x1 = *reinterpret_cast<const float4*>(xr + 256);
            float4 x2 = *reinterpret_cast<const float4*>(xr + 512);
            float4 x3 = *reinterpret_cast<const float4*>(xr + 768);
            float4 sr;
            sr.x = h4.x * x0.x + h4.y * x1.x + h4.z * x2.x + h4.w * x3.x;
            sr.y = h4.x * x0.y + h4.y * x1.y + h4.z * x2.y + h4.w * x3.y;
            sr.z = h4.x * x0.z + h4.y * x1.z + h4.z * x2.z + h4.w * x3.z;
            sr.w = h4.x * x0.w + h4.y * x1.w + h4.z * x2.w + h4.w * x3.w;
            uint2 pk;
            pk.x = cvtpk_bf16(sr.x, sr.y);
            pk.y = cvtpk_bf16(sr.z, sr.w);
            *reinterpret_cast<uint2*>(&xin[tok * XIN_STRIDE + cc]) = pk;
        }
    }
    __syncthreads();

    // ---- phase 4: f_out = Xin(8x256) @ W^T; wave w does ntiles 4w..4w+3 ----
    floatx4 accs[4];
    {
        const int arow = col & 7;
        short8 afr[8];
        #pragma unroll
        for (int ks = 0; ks < 8; ++ks)
            afr[ks] = *reinterpret_cast<const short8*>(&xin[arow * XIN_STRIDE + ks * 32 + quad * 8]);
        #pragma unroll
        for (int nt = 0; nt < 4; ++nt) {
            floatx4 acc = {0.0f, 0.0f, 0.0f, 0.0f};
            int ntile = w * 4 + nt;
            #pragma unroll
            for (int ks = 0; ks < 8; ++ks) {
                short8 b = *reinterpret_cast<const short8*>(&WF[(ntile * 8 + ks) * 512 + lane * 8]);
                acc = __builtin_amdgcn_mfma_f32_16x16x32_bf16(afr[ks], b, acc, 0, 0, 0);
            }
            accs[nt] = acc;
        }
    }
    // no barrier: phase 5 uses accs (regs), coef (stable), global x

    // ---- phase 5: out[tok][o][c] = sum_i P[o][i]*x[tok][i][c] + hpost[o]*f ----
    // D rows 8-15 dup toks 0-7: quads {0,2} toks 0-3, {1,3} toks 4-7.
    // o-head split: quads 0-1 store o=0,1; quads 2-3 store o=2,3.
    {
        const int o0 = (quad >> 1) * 2;
        #pragma unroll
        for (int r = 0; r < 4; ++r) {
            int tok = (quad & 1) * 4 + r;
            const float* cb = &coef[tok * 24];
            float hpoA = cb[4 + o0], hpoB = cb[5 + o0];
            float4 PA = *reinterpret_cast<const float4*>(cb + 8 + 4 * o0);
            float4 PB = *reinterpret_cast<const float4*>(cb + 12 + 4 * o0);
            long xb = base + (long)tok * 1024;
            long ob = xb + (long)o0 * 256;
            #pragma unroll
            for (int nt = 0; nt < 4; ++nt) {
                int c = (w * 4 + nt) * 16 + col;
                float f = accs[nt][r];
                const float* xr = x + xb + c;
                float x0 = xr[0],   x1 = xr[256];
                float x2 = xr[512], x3 = xr[768];
                out[ob + c]       = PA.x * x0 + PA.y * x1 + PA.z * x2 + PA.w * x3 + hpoA * f;
                out[ob + 256 + c] = PB.x * x0 + PB.y * x1 + PB.z * x2 + PB.w * x3 + hpoB * f;
            }
        }
    }
}

extern "C" void kernel_launch(void* const* d_in, const int* in_sizes, int n_in,
                              void* d_out, int out_size, void* d_ws, size_t ws_size,
                              hipStream_t stream) {
    const float* x    = (const float*)d_in[0];
    const float* phi  = (const float*)d_in[1];
    const float* bias = (const float*)d_in[2];
    const float* ap   = (const float*)d_in[3];
    const float* apo  = (const float*)d_in[4];
    const float* ar   = (const float*)d_in[5];
    const float* W    = (const float*)d_in[6];
    float* out = (float*)d_out;

    unsigned short* phiF = (unsigned short*)d_ws;           // 32768 bf16
    unsigned short* WF   = (unsigned short*)d_ws + 32768;   // 65536 bf16
    float* cbuf = (float*)((char*)d_ws + 196608);           // 32768 x 24 f32 = 3.1 MB

    mhc_prep<<<384, 256, 0, stream>>>(phi, W, phiF, WF);
    mhc_front<<<4096, 256, 0, stream>>>(x, bias, ap, apo, phiF, cbuf);
    mhc_sink<<<512, 64, 0, stream>>>(cbuf, ar);
    mhc_apply<<<4096, 256, 0, stream>>>(x, cbuf, WF, out);
}